// Round 25
// baseline (98.425 us; speedup 1.0000x reference)
//
#include <hip/hip_runtime.h>
#include <hip/hip_bf16.h>
#include <cstdint>
#include <cstddef>

// ---------- types ----------
using bf16x8 = __attribute__((ext_vector_type(8))) __bf16;
using f32x4  = __attribute__((ext_vector_type(4))) float;

__device__ __forceinline__ float b2f(unsigned short u) {
  union { unsigned u; float f; } x; x.u = ((unsigned)u) << 16; return x.f;
}
__device__ __forceinline__ unsigned short f2b(float f) {
  union { float f; unsigned u; } x; x.f = f;
  unsigned r = x.u + 0x7fffu + ((x.u >> 16) & 1u);
  return (unsigned short)(r >> 16);
}
// truncating cast: safe for P because l is computed (via MFMA) from the SAME bf16 values.
__device__ __forceinline__ unsigned short f2b_trunc(float f) {
  union { float f; unsigned u; } x; x.f = f;
  return (unsigned short)(x.u >> 16);
}

// async global->LDS, 16B per lane. dst must be wave-uniform base (HW adds lane*16).
__device__ __forceinline__ void gload_lds16(const void* g, void* l) {
  __builtin_amdgcn_global_load_lds(
      (const __attribute__((address_space(1))) void*)g,
      (__attribute__((address_space(3))) void*)l, 16, 0, 0);
}

__device__ __forceinline__ bf16x8 ldfrag(const unsigned short* p) {
  return *reinterpret_cast<const bf16x8*>(p);
}

// ---------- fused prep: all bf16 casts + RoPE sin/cos table, one kernel ----------
__global__ __launch_bounds__(256) void prep_kernel(const float* __restrict__ x,
                                                   const float* __restrict__ Wq,
                                                   const float* __restrict__ Wk,
                                                   const float* __restrict__ Wv,
                                                   const float* __restrict__ Wo,
                                                   unsigned short* __restrict__ xb,
                                                   unsigned short* __restrict__ wqkv,
                                                   unsigned short* __restrict__ wob,
                                                   float* __restrict__ st,
                                                   float* __restrict__ ct) {
  const int gid = blockIdx.x * 256 + threadIdx.x;  // 0..524287 (2048 blocks)
  if (gid < 65536) {                               // sincos: 2048*32 entries
    const int n = gid >> 5, j = gid & 31;
    const float inv = powf(10000.0f, -(float)j * (1.0f / 32.0f));
    const float ang = (float)n * inv;
    st[gid] = sinf(ang);
    ct[gid] = cosf(ang);
  }
  const int XW = 1048576;   // x: 4096*1024 floats = 1M float4
  const int WW = 262144;    // each W: 1024*1024 floats = 256K float4
#pragma unroll
  for (int it = 0; it < 4; ++it) {
    const int i = gid + it * 524288;  // total 2M float4
    const float* s; unsigned short* d; int j;
    if (i < XW)                { s = x;  d = xb;              j = i; }
    else if (i < XW + WW)      { s = Wq; d = wqkv;            j = i - XW; }
    else if (i < XW + 2 * WW)  { s = Wk; d = wqkv + 1048576;  j = i - XW - WW; }
    else if (i < XW + 3 * WW)  { s = Wv; d = wqkv + 2097152;  j = i - XW - 2 * WW; }
    else                       { s = Wo; d = wob;             j = i - XW - 3 * WW; }
    float4 v = reinterpret_cast<const float4*>(s)[j];
    ushort4 o;
    o.x = f2b(v.x); o.y = f2b(v.y); o.z = f2b(v.z); o.w = f2b(v.w);
    reinterpret_cast<ushort4*>(d)[j] = o;
  }
}

// ---------- 256x192 8-wave GEMM (qkv proj), grid=256, fused RoPE ----------
// Minimal-barrier K-loop (R21, measured best): stage all 7 next-tile loads
// upfront; 4 q-phases with NO intra-tile barriers; single vmcnt(0)+barrier/tile.
__global__ __launch_bounds__(512) void gemm256(const unsigned short* __restrict__ A,
                                               const unsigned short* __restrict__ B,
                                               unsigned short* __restrict__ Qo,
                                               unsigned short* __restrict__ Ko,
                                               unsigned short* __restrict__ Vt,
                                               const float* __restrict__ st,
                                               const float* __restrict__ ct,
                                               const float* __restrict__ bq,
                                               const float* __restrict__ bk,
                                               const float* __restrict__ bv,
                                               int M, int N, int K, int TN) {
  extern __shared__ __align__(16) unsigned short sm[];  // [2][A 256x64 | B 192x64]
  const int tid = threadIdx.x, lane = tid & 63, wave = tid >> 6;
  const int lr = lane & 15, lk = lane >> 4;
  const int wr = wave >> 2, wc = wave & 3;  // 2 x 4 waves; wave = 128 rows x 48 cols

  // XCD-bijective swizzle (grid 256, %8==0)
  int wg = (int)blockIdx.x;
  const int cpx = (int)gridDim.x >> 3;
  wg = (wg & 7) * cpx + (wg >> 3);
  const int bn = (wg % TN) * 192, bm = (wg / TN) * 256;

  // staging: issue i covers 64 rows; thread -> row srow (0..63), 16B chunk.
  const int srow = wave * 8 + (lane >> 3);
  const int scol = (((lane & 7) * 16) ^ (((lane >> 3) & 7) << 4)) >> 1;  // elems
  const unsigned short* Ag = A + (size_t)(bm + srow) * K + scol;
  const unsigned short* Bg = B + (size_t)(bn + srow) * K + scol;

  auto issueA = [&](int kt, int nb, int i) {  // i in 0..3 (256 rows)
    gload_lds16(Ag + (size_t)(i * 64) * K + (size_t)kt * 64,
                sm + nb * 28672 + wave * 512 + i * 4096);
  };
  auto issueB = [&](int kt, int nb, int i) {  // i in 0..2 (192 rows)
    gload_lds16(Bg + (size_t)(i * 64) * K + (size_t)kt * 64,
                sm + nb * 28672 + 16384 + wave * 512 + i * 4096);
  };

  f32x4 acc[8][3] = {};
  const int swz = (lr & 7) << 4;  // frag rows are lr mod 8 (16/48 = 0 mod 8)
  const int NT = K / 64;

  // prologue: full first tile (7 loads), single drain
#pragma unroll
  for (int i = 0; i < 3; ++i) issueB(0, 0, i);
#pragma unroll
  for (int i = 0; i < 4; ++i) issueA(0, 0, i);
  asm volatile("s_waitcnt vmcnt(0)" ::: "memory");
  __builtin_amdgcn_s_barrier();

  for (int kt = 0; kt < NT; ++kt) {
    const int cur = kt & 1, nb = cur ^ 1;
    const bool pf = (kt + 1 < NT);

    if (pf) {  // stage entire next tile upfront (7 async loads, land in nb)
#pragma unroll
      for (int i = 0; i < 3; ++i) issueB(kt + 1, nb, i);
#pragma unroll
      for (int i = 0; i < 4; ++i) issueA(kt + 1, nb, i);
    }

    const unsigned short* Ab = sm + cur * 28672 + wr * 8192;   // wave's 128 A rows
    const unsigned short* Bb = sm + cur * 28672 + 16384;       // full 192 B rows

    bf16x8 b[3][2];
#pragma unroll
    for (int n = 0; n < 3; ++n)
#pragma unroll
      for (int kk = 0; kk < 2; ++kk)
        b[n][kk] = ldfrag(&Bb[(wc * 48 + n * 16 + lr) * 64 + (((kk * 64 + lk * 16) ^ swz) >> 1)]);

#pragma unroll
    for (int q = 0; q < 4; ++q) {
      bf16x8 a[2][2];
#pragma unroll
      for (int m = 0; m < 2; ++m)
#pragma unroll
        for (int kk = 0; kk < 2; ++kk)
          a[m][kk] = ldfrag(&Ab[((q * 2 + m) * 16 + lr) * 64 + (((kk * 64 + lk * 16) ^ swz) >> 1)]);
      __builtin_amdgcn_s_setprio(1);
#pragma unroll
      for (int kk = 0; kk < 2; ++kk)
#pragma unroll
        for (int m = 0; m < 2; ++m)
#pragma unroll
          for (int n = 0; n < 3; ++n)
            acc[q * 2 + m][n] =
                __builtin_amdgcn_mfma_f32_16x16x32_bf16(a[m][kk], b[n][kk], acc[q * 2 + m][n], 0, 0, 0);
      __builtin_amdgcn_s_setprio(0);
    }

    if (pf) {  // single sync point per K-tile
      asm volatile("s_waitcnt vmcnt(0)" ::: "memory");
      __builtin_amdgcn_s_barrier();
    }
  }

  __syncthreads();  // staged LDS free for epilogue reuse

  const int btok = bm >> 11;          // batch (2048 tokens each)
  const int ntok0 = bm & 2047;        // tile's first token (batch-local)

  // ---- per-frag: v heads -> direct store; q/k heads -> LDS (swizzled granules) ----
#pragma unroll
  for (int n = 0; n < 3; ++n) {
    const int col = bn + wc * 48 + n * 16 + lr;
    if (col >= 2048) {  // v: direct register -> Vt[bh][d][n'] (sigma'd)
      const int vcol = col - 2048;
      const float bvv = bv[vcol];
      const int h = vcol >> 6, d = vcol & 63;
      unsigned short* vrow = Vt + ((size_t)((btok * 16 + h) * 64 + d)) * 2048;
#pragma unroll
      for (int mu = 0; mu < 4; ++mu) {
        uint4 w;
        w.x = (unsigned)f2b(acc[2 * mu][n][0] + bvv)     | ((unsigned)f2b(acc[2 * mu][n][1] + bvv) << 16);
        w.y = (unsigned)f2b(acc[2 * mu][n][2] + bvv)     | ((unsigned)f2b(acc[2 * mu][n][3] + bvv) << 16);
        w.z = (unsigned)f2b(acc[2 * mu + 1][n][0] + bvv) | ((unsigned)f2b(acc[2 * mu + 1][n][1] + bvv) << 16);
        w.w = (unsigned)f2b(acc[2 * mu + 1][n][2] + bvv) | ((unsigned)f2b(acc[2 * mu + 1][n][3] + bvv) << 16);
        const int ncol = ntok0 + wr * 128 + mu * 32 + 8 * lk;
        *reinterpret_cast<uint4*>(vrow + ncol) = w;
      }
    } else {  // q/k: store into sm[256][192], granule-swizzled (g ^= row&7, in-band)
      const float bvv = (col < 1024) ? bq[col] : bk[col & 1023];
      const int lcol = wc * 48 + n * 16 + lr;
#pragma unroll
      for (int m = 0; m < 8; ++m)
#pragma unroll
        for (int r = 0; r < 4; ++r) {
          const int lrow = wr * 128 + m * 16 + lk * 4 + r;
          const int g2 = (lcol >> 3) ^ (lrow & 7);
          sm[lrow * 192 + (g2 << 3) + (lcol & 7)] = f2b(acc[m][n][r] + bvv);
        }
    }
  }
  __syncthreads();

  // ---- q/k read + RoPE + write pass: thread-head over 256 rows x nqk heads ----
  const int nqk = min(3, max(0, (2048 - bn) >> 6));
  for (int t = tid; t < 256 * nqk; t += 512) {
    const int hh = t >> 8, row = t & 255;
    const int ntok = ntok0 + row;
    const int col0 = bn + hh * 64;
    const bool isq = col0 < 1024;
    const int h = (col0 & 1023) >> 6;
    const float* ctp = ct + ntok * 32;
    const float* stp = st + ntok * 32;
    unsigned short xr[64];
#pragma unroll
    for (int i = 0; i < 8; ++i) {
      const int g = (hh * 8 + i) ^ (row & 7);
      *reinterpret_cast<int4*>(&xr[i * 8]) =
          *reinterpret_cast<const int4*>(&sm[row * 192 + g * 8]);
    }
    unsigned short out[64];
#pragma unroll
    for (int i = 0; i < 32; ++i) {
      const float c = ctp[i], s = stp[i];
      float o1 = b2f(xr[i]) * c - b2f(xr[2 * i + 1]) * s;        // d = i
      float o2 = b2f(xr[32 + i]) * c + b2f(xr[2 * i]) * s;       // d = 32 + i
      if (isq) { o1 *= 0.18033688f; o2 *= 0.18033688f; }         // (1/8)*log2(e)
      out[i] = f2b(o1);
      out[32 + i] = f2b(o2);
    }
    unsigned short* dst =
        (isq ? Qo : Ko) + ((size_t)((btok * 16 + h) * 2048 + ntok)) * 64;
#pragma unroll
    for (int i = 0; i < 8; ++i)
      *reinterpret_cast<int4*>(dst + i * 8) =
          *reinterpret_cast<const int4*>(&out[i * 8]);
  }
}

// ---------- out-proj GEMM: 128x128, BK=64, double-buffered (R20, measured win) ----------
__global__ __launch_bounds__(256) void gemm_out(const unsigned short* __restrict__ A,
                                                const unsigned short* __restrict__ B,
                                                float* __restrict__ C,
                                                const float* __restrict__ bias,
                                                int M, int N, int K) {
  extern __shared__ __align__(16) unsigned short sm[];  // [2][A 128x64 | B 128x64]
  const int tid = threadIdx.x, lane = tid & 63, wave = tid >> 6;
  const int lr = lane & 15, lk = lane >> 4;
  const int wr = wave >> 1, wc = wave & 1;  // 2 x 2 waves
  const int bm = blockIdx.y * 128, bn = blockIdx.x * 128;

  const int srow = tid >> 3;
  const int scol = (((tid & 7) * 16) ^ ((srow & 7) << 4)) >> 1;  // elems (swizzled)
  const unsigned short* Ag = A + (size_t)(bm + srow) * K + scol;
  const unsigned short* Bg = B + (size_t)(bn + srow) * K + scol;

  auto stage = [&](int kt, int nb) {
    const size_t ko = (size_t)kt * 64;
    unsigned short* base = sm + nb * 16384 + wave * 512;  // per-wave sub-slot
#pragma unroll
    for (int i = 0; i < 4; ++i)   // A: 128 rows (32 per issue)
      gload_lds16(Ag + (size_t)(i * 32) * K + ko, base + i * 2048);
#pragma unroll
    for (int i = 0; i < 4; ++i)   // B: 128 rows
      gload_lds16(Bg + (size_t)(i * 32) * K + ko, base + 8192 + i * 2048);
  };

  f32x4 acc[4][4] = {};
  const int swz = (lr & 7) << 4;
  const int NT = K / 64;  // 16

  stage(0, 0);
  asm volatile("s_waitcnt vmcnt(0)" ::: "memory");
  __builtin_amdgcn_s_barrier();

  for (int kt = 0; kt < NT; ++kt) {
    const int cur = kt & 1;
    const bool pf = (kt + 1 < NT);
    if (pf) stage(kt + 1, cur ^ 1);

    const unsigned short* Ab = sm + cur * 16384 + (size_t)wr * 64 * 64;
    const unsigned short* Bb = sm + cur * 16384 + 8192 + (size_t)wc * 64 * 64;

    bf16x8 b[4][2];
#pragma unroll
    for (int n = 0; n < 4; ++n)
#pragma unroll
      for (int kk = 0; kk < 2; ++kk)
        b[n][kk] = ldfrag(&Bb[(n * 16 + lr) * 64 + (((kk * 64 + lk * 16) ^ swz) >> 1)]);

#pragma unroll
    for (int m = 0; m < 4; ++m) {
      bf16x8 a[2];
#pragma unroll
      for (int kk = 0; kk < 2; ++kk)
        a[kk] = ldfrag(&Ab[(m * 16 + lr) * 64 + (((kk * 64 + lk * 16) ^ swz) >> 1)]);
      __builtin_amdgcn_s_setprio(1);
#pragma unroll
      for (int kk = 0; kk < 2; ++kk)
#pragma unroll
        for (int n = 0; n < 4; ++n)
          acc[m][n] = __builtin_amdgcn_mfma_f32_16x16x32_bf16(a[kk], b[n][kk], acc[m][n], 0, 0, 0);
      __builtin_amdgcn_s_setprio(0);
    }

    if (pf) {
      asm volatile("s_waitcnt vmcnt(0)" ::: "memory");
      __builtin_amdgcn_s_barrier();
    }
  }

  // epilogue: f32 + bias
#pragma unroll
  for (int m = 0; m < 4; ++m) {
#pragma unroll
    for (int n = 0; n < 4; ++n) {
      const int col = bn + wc * 64 + n * 16 + lr;
      const float bvv = bias[col];
#pragma unroll
      for (int r = 0; r < 4; ++r) {
        const int row = bm + wr * 64 + m * 16 + lk * 4 + r;
        C[(size_t)row * N + col] = acc[m][n][r] + bvv;
      }
    }
  }
}

// ---------- Flash attention (swapped-QK^T, in-register P, zero-shuffle PV) ----------
__global__ __launch_bounds__(512) void flash_kernel(const unsigned short* __restrict__ Q,
                                                    const unsigned short* __restrict__ Kb,
                                                    const unsigned short* __restrict__ Vt,
                                                    unsigned short* __restrict__ Out, int N) {
  extern __shared__ __align__(16) unsigned short smem[];
  unsigned short* KsB = smem;           // [2][128*64]
  unsigned short* VsB = smem + 16384;   // [2][64*128] sigma-permuted cols

  const int tid = threadIdx.x;
  const int lane = tid & 63, wave = tid >> 6;
  const int lr = lane & 15, lk = lane >> 4;
  const int bh = blockIdx.x;            // XCD pin
  const int x = blockIdx.y;             // 0..7
  const int qtA = x, qtB = 15 - x;
  const int ntA = x + 1;                // + (16-x) = 17 phases, uniform
  const unsigned short* Qh = Q + (size_t)bh * N * 64;
  const unsigned short* Kh = Kb + (size_t)bh * N * 64;
  const unsigned short* Vh = Vt + (size_t)bh * 64 * N;

  const int wrowA = qtA * 128 + wave * 16;
  const int wrowB = qtB * 128 + wave * 16;

  const int kr = tid >> 3;
  const int kcb = ((tid & 7) * 16) ^ ((kr & 7) << 4);
  const unsigned short* Kg0 = Kh + (size_t)kr * 64 + (kcb >> 1);
  const int vr = tid >> 4;
  const int vcb = ((tid & 15) * 16) ^ ((vr & 7) << 4);
  const unsigned short* Vg0 = Vh + (size_t)vr * N + (vcb >> 1);

  auto stage = [&](int buf, int tk) {
    const unsigned short* kp = Kg0 + (size_t)tk * 8192;
    const unsigned short* vp = Vg0 + (size_t)tk * 128;
    unsigned short* kl = KsB + buf * 8192 + wave * 512;
    unsigned short* vl = VsB + buf * 8192 + wave * 512;
    gload_lds16(kp, kl);
    gload_lds16(kp + 4096, kl + 4096);
    gload_lds16(vp, vl);
    gload_lds16(vp + (size_t)32 * N, vl + 4096);
  };

  stage(0, 0);

  bf16x8 qA0 = ldfrag(&Qh[(size_t)(wrowA + lr) * 64 + lk * 8]);
  bf16x8 qA1 = ldfrag(&Qh[(size_t)(wrowA + lr) * 64 + 32 + lk * 8]);
  bf16x8 qB0 = ldfrag(&Qh[(size_t)(wrowB + lr) * 64 + lk * 8]);
  bf16x8 qB1 = ldfrag(&Qh[(size_t)(wrowB + lr) * 64 + 32 + lk * 8]);

  bf16x8 ones;
  {
    union { unsigned short u; __bf16 b; } one; one.u = 0x3F80;
#pragma unroll
    for (int j = 0; j < 8; ++j) ones[j] = one.b;
  }

  const float NEG = -1e30f;  // finite sentinel: no -inf anywhere in this kernel
  f32x4 oacc[4] = {};   // O^T: [d-tile ni][d-sub r], q = lr
  f32x4 lacc = {};      // all 4 entries = l[q]
  float m_run = NEG;

  auto compute_phase = [&](int buf, bf16x8 q0, bf16x8 q1, bool diag) {
    const unsigned short* Ksb = KsB + buf * 8192;
    const unsigned short* Vsb = VsB + buf * 8192;
    f32x4 s[8];
#pragma unroll
    for (int ni = 0; ni < 8; ++ni) s[ni] = f32x4{0.f, 0.f, 0.f, 0.f};
    __builtin_amdgcn_s_setprio(1);
#pragma unroll
    for (int ni = 0; ni < 8; ++ni) {
      const int R = ni * 16 + lr;
      const int sw = (R & 7) << 4;
      bf16x8 kf0 = ldfrag(&Ksb[R * 64 + (((lk * 16) ^ sw) >> 1)]);
      bf16x8 kf1 = ldfrag(&Ksb[R * 64 + (((64 + lk * 16) ^ sw) >> 1)]);
      s[ni] = __builtin_amdgcn_mfma_f32_16x16x32_bf16(kf0, q0, s[ni], 0, 0, 0);
      s[ni] = __builtin_amdgcn_mfma_f32_16x16x32_bf16(kf1, q1, s[ni], 0, 0, 0);
    }
    __builtin_amdgcn_s_setprio(0);

    if (diag) {
      const int ql = wave * 16 + lr;
#pragma unroll
      for (int ni = 0; ni < 8; ++ni)
#pragma unroll
        for (int r = 0; r < 4; ++r)
          if (ni * 16 + lk * 4 + r > ql) s[ni][r] = NEG;
    }

    float mx = s[0][0];
#pragma unroll
    for (int ni = 0; ni < 8; ++ni)
#pragma unroll
      for (int r = 0; r < 4; ++r)
        if (ni || r) mx = fmaxf(mx, s[ni][r]);
    mx = fmaxf(mx, __shfl_xor(mx, 16, 64));
    mx = fmaxf(mx, __shfl_xor(mx, 32, 64));

    if (!__all(mx - m_run <= 8.0f)) {  // defer-max (THR=8 in log2 units)
      float nm = fmaxf(m_run, mx);
      float alpha = __builtin_amdgcn_exp2f(m_run - nm);
      m_run = nm;
#pragma unroll
      for (int ni = 0; ni < 4; ++ni) oacc[ni] *= alpha;
      lacc *= alpha;
    }

    unsigned pk[8][2];
#pragma unroll
    for (int ni = 0; ni < 8; ++ni) {
      float p0 = __builtin_amdgcn_exp2f(s[ni][0] - m_run);
      float p1 = __builtin_amdgcn_exp2f(s[ni][1] - m_run);
      float p2 = __builtin_amdgcn_exp2f(s[ni][2] - m_run);
      float p3 = __builtin_amdgcn_exp2f(s[ni][3] - m_run);
      pk[ni][0] = (unsigned)f2b_trunc(p0) | ((unsigned)f2b_trunc(p1) << 16);
      pk[ni][1] = (unsigned)f2b_trunc(p2) | ((unsigned)f2b_trunc(p3) << 16);
    }

    __builtin_amdgcn_s_setprio(1);
#pragma unroll
    for (int c = 0; c < 4; ++c) {
      union { unsigned u[4]; bf16x8 v; } pb;
      pb.u[0] = pk[2 * c][0];
      pb.u[1] = pk[2 * c][1];
      pb.u[2] = pk[2 * c + 1][0];
      pb.u[3] = pk[2 * c + 1][1];
      lacc = __builtin_amdgcn_mfma_f32_16x16x32_bf16(ones, pb.v, lacc, 0, 0, 0);
      const int cb = c * 64 + lk * 16;
#pragma unroll
      for (int ni = 0; ni < 4; ++ni) {
        const int RV = ni * 16 + lr;
        bf16x8 vf = ldfrag(&Vsb[RV * 128 + ((cb ^ ((RV & 7) << 4)) >> 1)]);
        oacc[ni] = __builtin_amdgcn_mfma_f32_16x16x32_bf16(vf, pb.v, oacc[ni], 0, 0, 0);
      }
    }
    __builtin_amdgcn_s_setprio(0);
  };

  const int b = bh >> 4, h = bh & 15;
  auto epilogue = [&](int wrow0) {
    const float rl = 1.0f / lacc[0];
    const int q = wrow0 + lr;
#pragma unroll
    for (int ni = 0; ni < 4; ++ni) {
      uint2 w;
      w.x = (unsigned)f2b(oacc[ni][0] * rl) | ((unsigned)f2b(oacc[ni][1] * rl) << 16);
      w.y = (unsigned)f2b(oacc[ni][2] * rl) | ((unsigned)f2b(oacc[ni][3] * rl) << 16);
      *reinterpret_cast<uint2*>(
          &Out[((size_t)(b * N + q)) * 1024 + h * 64 + ni * 16 + lk * 4]) = w;
    }
  };

  __syncthreads();

  int buf = 0;
  for (int p = 0; p < 17; ++p) {
    if (p + 1 < 17) {
      int tk2 = (p + 1 < ntA) ? (p + 1) : (p + 1 - ntA);
      stage(buf ^ 1, tk2);
    }
    if (p == ntA) {
      epilogue(wrowA);
#pragma unroll
      for (int ni = 0; ni < 4; ++ni) oacc[ni] = f32x4{0.f, 0.f, 0.f, 0.f};
      lacc = f32x4{0.f, 0.f, 0.f, 0.f};
      m_run = NEG;
    }
    if (p < ntA) compute_phase(buf, qA0, qA1, p == ntA - 1);
    else         compute_phase(buf, qB0, qB1, p == 16);
    __syncthreads();
    buf ^= 1;
  }
  epilogue(wrowB);
}

// ---------- launch ----------
extern "C" void kernel_launch(void* const* d_in, const int* in_sizes, int n_in,
                              void* d_out, int out_size, void* d_ws, size_t ws_size,
                              hipStream_t stream) {
  const int B = 2, N = 2048, E = 1024, C = 1024, NC = 3072;
  const int M = B * N;  // 4096

  const float* x  = (const float*)d_in[0];
  const float* Wq = (const float*)d_in[1];
  const float* bq = (const float*)d_in[2];
  const float* Wk = (const float*)d_in[3];
  const float* bk = (const float*)d_in[4];
  const float* Wv = (const float*)d_in[5];
  const float* bv = (const float*)d_in[6];
  const float* Wo = (const float*)d_in[7];
  const float* bo = (const float*)d_in[8];

  char* w = (char*)d_ws;
  size_t off = 0;
  auto alloc = [&](size_t bytes) {
    void* p = w + off;
    off += (bytes + 255) & ~(size_t)255;
    return p;
  };
  unsigned short* xb    = (unsigned short*)alloc((size_t)M * E * 2);
  unsigned short* wqkv  = (unsigned short*)alloc((size_t)NC * E * 2);
  unsigned short* wob   = (unsigned short*)alloc((size_t)E * C * 2);
  unsigned short* qb    = (unsigned short*)alloc((size_t)B * 16 * N * 64 * 2);
  unsigned short* kb    = (unsigned short*)alloc((size_t)B * 16 * N * 64 * 2);
  unsigned short* vt    = (unsigned short*)alloc((size_t)B * 16 * 64 * N * 2);
  unsigned short* attnb = (unsigned short*)alloc((size_t)M * C * 2);
  float* sin_t = (float*)alloc((size_t)N * 32 * 4);
  float* cos_t = (float*)alloc((size_t)N * 32 * 4);

  // fused prep: all bf16 casts + sin/cos table in ONE kernel (grid-stride)
  prep_kernel<<<2048, 256, 0, stream>>>(x, Wq, Wk, Wv, Wo, xb, wqkv, wob, sin_t, cos_t);

  // QKV projection + fused RoPE/relayout: 256x192 tiles, minimal-barrier K-loop
  static const int GEMM_LDS = 114688;
  hipFuncSetAttribute(reinterpret_cast<const void*>(gemm256),
                      hipFuncAttributeMaxDynamicSharedMemorySize, GEMM_LDS);
  gemm256<<<dim3((NC / 192) * (M / 256)), 512, GEMM_LDS, stream>>>(
      xb, wqkv, qb, kb, vt, sin_t, cos_t, bq, bk, bv, M, NC, E, NC / 192);

  // causal flash attention: 256 blocks x 512 thr, 64KB LDS, XCD-pinned bh
  static const int FLASH_LDS = 65536;
  hipFuncSetAttribute(reinterpret_cast<const void*>(flash_kernel),
                      hipFuncAttributeMaxDynamicSharedMemorySize, FLASH_LDS);
  flash_kernel<<<dim3(B * 16, 8), 512, FLASH_LDS, stream>>>(qb, kb, vt, attnb, N);

  // output projection: 128x128 BK=64 dbuf GEMM + bo -> f32 d_out
  static const int OUT_LDS = 65536;
  hipFuncSetAttribute(reinterpret_cast<const void*>(gemm_out),
                      hipFuncAttributeMaxDynamicSharedMemorySize, OUT_LDS);
  gemm_out<<<dim3(E / 128, M / 128), 256, OUT_LDS, stream>>>(
      attnb, wob, (float*)d_out, bo, M, E, C);
}

// Round 26
// 98.073 us; speedup vs baseline: 1.0036x; 1.0036x over previous
//
#include <hip/hip_runtime.h>
#include <hip/hip_bf16.h>
#include <cstdint>
#include <cstddef>

// ---------- types ----------
using bf16x8 = __attribute__((ext_vector_type(8))) __bf16;
using f32x4  = __attribute__((ext_vector_type(4))) float;

__device__ __forceinline__ float b2f(unsigned short u) {
  union { unsigned u; float f; } x; x.u = ((unsigned)u) << 16; return x.f;
}
__device__ __forceinline__ unsigned short f2b(float f) {
  union { float f; unsigned u; } x; x.f = f;
  unsigned r = x.u + 0x7fffu + ((x.u >> 16) & 1u);
  return (unsigned short)(r >> 16);
}
// truncating cast: safe for P because l is computed (via MFMA) from the SAME bf16 values.
__device__ __forceinline__ unsigned short f2b_trunc(float f) {
  union { float f; unsigned u; } x; x.f = f;
  return (unsigned short)(x.u >> 16);
}

// async global->LDS, 16B per lane. dst must be wave-uniform base (HW adds lane*16).
__device__ __forceinline__ void gload_lds16(const void* g, void* l) {
  __builtin_amdgcn_global_load_lds(
      (const __attribute__((address_space(1))) void*)g,
      (__attribute__((address_space(3))) void*)l, 16, 0, 0);
}

__device__ __forceinline__ bf16x8 ldfrag(const unsigned short* p) {
  return *reinterpret_cast<const bf16x8*>(p);
}

// ---------- fused prep: all bf16 casts + RoPE sin/cos table, one kernel ----------
__global__ __launch_bounds__(256) void prep_kernel(const float* __restrict__ x,
                                                   const float* __restrict__ Wq,
                                                   const float* __restrict__ Wk,
                                                   const float* __restrict__ Wv,
                                                   const float* __restrict__ Wo,
                                                   unsigned short* __restrict__ xb,
                                                   unsigned short* __restrict__ wqkv,
                                                   unsigned short* __restrict__ wob,
                                                   float* __restrict__ st,
                                                   float* __restrict__ ct) {
  const int gid = blockIdx.x * 256 + threadIdx.x;  // 0..524287 (2048 blocks)
  if (gid < 65536) {                               // sincos: 2048*32 entries
    const int n = gid >> 5, j = gid & 31;
    const float inv = powf(10000.0f, -(float)j * (1.0f / 32.0f));
    const float ang = (float)n * inv;
    st[gid] = sinf(ang);
    ct[gid] = cosf(ang);
  }
  const int XW = 1048576;   // x: 4096*1024 floats = 1M float4
  const int WW = 262144;    // each W: 1024*1024 floats = 256K float4
#pragma unroll
  for (int it = 0; it < 4; ++it) {
    const int i = gid + it * 524288;  // total 2M float4
    const float* s; unsigned short* d; int j;
    if (i < XW)                { s = x;  d = xb;              j = i; }
    else if (i < XW + WW)      { s = Wq; d = wqkv;            j = i - XW; }
    else if (i < XW + 2 * WW)  { s = Wk; d = wqkv + 1048576;  j = i - XW - WW; }
    else if (i < XW + 3 * WW)  { s = Wv; d = wqkv + 2097152;  j = i - XW - 2 * WW; }
    else                       { s = Wo; d = wob;             j = i - XW - 3 * WW; }
    float4 v = reinterpret_cast<const float4*>(s)[j];
    ushort4 o;
    o.x = f2b(v.x); o.y = f2b(v.y); o.z = f2b(v.z); o.w = f2b(v.w);
    reinterpret_cast<ushort4*>(d)[j] = o;
  }
}

// ---------- 256x192 8-wave GEMM (qkv proj), grid=256, fused RoPE ----------
// Minimal-barrier K-loop (R21, measured best): stage all 7 next-tile loads
// upfront; 4 q-phases with NO intra-tile barriers; single vmcnt(0)+barrier/tile.
__global__ __launch_bounds__(512) void gemm256(const unsigned short* __restrict__ A,
                                               const unsigned short* __restrict__ B,
                                               unsigned short* __restrict__ Qo,
                                               unsigned short* __restrict__ Ko,
                                               unsigned short* __restrict__ Vt,
                                               const float* __restrict__ st,
                                               const float* __restrict__ ct,
                                               const float* __restrict__ bq,
                                               const float* __restrict__ bk,
                                               const float* __restrict__ bv,
                                               int M, int N, int K, int TN) {
  extern __shared__ __align__(16) unsigned short sm[];  // [2][A 256x64 | B 192x64]
  const int tid = threadIdx.x, lane = tid & 63, wave = tid >> 6;
  const int lr = lane & 15, lk = lane >> 4;
  const int wr = wave >> 2, wc = wave & 3;  // 2 x 4 waves; wave = 128 rows x 48 cols

  // XCD-bijective swizzle (grid 256, %8==0)
  int wg = (int)blockIdx.x;
  const int cpx = (int)gridDim.x >> 3;
  wg = (wg & 7) * cpx + (wg >> 3);
  const int bn = (wg % TN) * 192, bm = (wg / TN) * 256;

  // staging: issue i covers 64 rows; thread -> row srow (0..63), 16B chunk.
  const int srow = wave * 8 + (lane >> 3);
  const int scol = (((lane & 7) * 16) ^ (((lane >> 3) & 7) << 4)) >> 1;  // elems
  const unsigned short* Ag = A + (size_t)(bm + srow) * K + scol;
  const unsigned short* Bg = B + (size_t)(bn + srow) * K + scol;

  auto issueA = [&](int kt, int nb, int i) {  // i in 0..3 (256 rows)
    gload_lds16(Ag + (size_t)(i * 64) * K + (size_t)kt * 64,
                sm + nb * 28672 + wave * 512 + i * 4096);
  };
  auto issueB = [&](int kt, int nb, int i) {  // i in 0..2 (192 rows)
    gload_lds16(Bg + (size_t)(i * 64) * K + (size_t)kt * 64,
                sm + nb * 28672 + 16384 + wave * 512 + i * 4096);
  };

  f32x4 acc[8][3] = {};
  const int swz = (lr & 7) << 4;  // frag rows are lr mod 8 (16/48 = 0 mod 8)
  const int NT = K / 64;

  // prologue: full first tile (7 loads), single drain
#pragma unroll
  for (int i = 0; i < 3; ++i) issueB(0, 0, i);
#pragma unroll
  for (int i = 0; i < 4; ++i) issueA(0, 0, i);
  asm volatile("s_waitcnt vmcnt(0)" ::: "memory");
  __builtin_amdgcn_s_barrier();

  for (int kt = 0; kt < NT; ++kt) {
    const int cur = kt & 1, nb = cur ^ 1;
    const bool pf = (kt + 1 < NT);

    if (pf) {  // stage entire next tile upfront (7 async loads, land in nb)
#pragma unroll
      for (int i = 0; i < 3; ++i) issueB(kt + 1, nb, i);
#pragma unroll
      for (int i = 0; i < 4; ++i) issueA(kt + 1, nb, i);
    }

    const unsigned short* Ab = sm + cur * 28672 + wr * 8192;   // wave's 128 A rows
    const unsigned short* Bb = sm + cur * 28672 + 16384;       // full 192 B rows

    bf16x8 b[3][2];
#pragma unroll
    for (int n = 0; n < 3; ++n)
#pragma unroll
      for (int kk = 0; kk < 2; ++kk)
        b[n][kk] = ldfrag(&Bb[(wc * 48 + n * 16 + lr) * 64 + (((kk * 64 + lk * 16) ^ swz) >> 1)]);

#pragma unroll
    for (int q = 0; q < 4; ++q) {
      bf16x8 a[2][2];
#pragma unroll
      for (int m = 0; m < 2; ++m)
#pragma unroll
        for (int kk = 0; kk < 2; ++kk)
          a[m][kk] = ldfrag(&Ab[((q * 2 + m) * 16 + lr) * 64 + (((kk * 64 + lk * 16) ^ swz) >> 1)]);
      __builtin_amdgcn_s_setprio(1);
#pragma unroll
      for (int kk = 0; kk < 2; ++kk)
#pragma unroll
        for (int m = 0; m < 2; ++m)
#pragma unroll
          for (int n = 0; n < 3; ++n)
            acc[q * 2 + m][n] =
                __builtin_amdgcn_mfma_f32_16x16x32_bf16(a[m][kk], b[n][kk], acc[q * 2 + m][n], 0, 0, 0);
      __builtin_amdgcn_s_setprio(0);
    }

    if (pf) {  // single sync point per K-tile
      asm volatile("s_waitcnt vmcnt(0)" ::: "memory");
      __builtin_amdgcn_s_barrier();
    }
  }

  __syncthreads();  // staged LDS free for epilogue reuse

  const int btok = bm >> 11;          // batch (2048 tokens each)
  const int ntok0 = bm & 2047;        // tile's first token (batch-local)

  // ---- per-frag: v heads -> direct store; q/k heads -> LDS (swizzled granules) ----
#pragma unroll
  for (int n = 0; n < 3; ++n) {
    const int col = bn + wc * 48 + n * 16 + lr;
    if (col >= 2048) {  // v: direct register -> Vt[bh][d][n'] (sigma'd)
      const int vcol = col - 2048;
      const float bvv = bv[vcol];
      const int h = vcol >> 6, d = vcol & 63;
      unsigned short* vrow = Vt + ((size_t)((btok * 16 + h) * 64 + d)) * 2048;
#pragma unroll
      for (int mu = 0; mu < 4; ++mu) {
        uint4 w;
        w.x = (unsigned)f2b(acc[2 * mu][n][0] + bvv)     | ((unsigned)f2b(acc[2 * mu][n][1] + bvv) << 16);
        w.y = (unsigned)f2b(acc[2 * mu][n][2] + bvv)     | ((unsigned)f2b(acc[2 * mu][n][3] + bvv) << 16);
        w.z = (unsigned)f2b(acc[2 * mu + 1][n][0] + bvv) | ((unsigned)f2b(acc[2 * mu + 1][n][1] + bvv) << 16);
        w.w = (unsigned)f2b(acc[2 * mu + 1][n][2] + bvv) | ((unsigned)f2b(acc[2 * mu + 1][n][3] + bvv) << 16);
        const int ncol = ntok0 + wr * 128 + mu * 32 + 8 * lk;
        *reinterpret_cast<uint4*>(vrow + ncol) = w;
      }
    } else {  // q/k: store into sm[256][192], granule-swizzled (g ^= row&7, in-band)
      const float bvv = (col < 1024) ? bq[col] : bk[col & 1023];
      const int lcol = wc * 48 + n * 16 + lr;
#pragma unroll
      for (int m = 0; m < 8; ++m)
#pragma unroll
        for (int r = 0; r < 4; ++r) {
          const int lrow = wr * 128 + m * 16 + lk * 4 + r;
          const int g2 = (lcol >> 3) ^ (lrow & 7);
          sm[lrow * 192 + (g2 << 3) + (lcol & 7)] = f2b(acc[m][n][r] + bvv);
        }
    }
  }
  __syncthreads();

  // ---- q/k read + RoPE + write pass: thread-head over 256 rows x nqk heads ----
  const int nqk = min(3, max(0, (2048 - bn) >> 6));
  for (int t = tid; t < 256 * nqk; t += 512) {
    const int hh = t >> 8, row = t & 255;
    const int ntok = ntok0 + row;
    const int col0 = bn + hh * 64;
    const bool isq = col0 < 1024;
    const int h = (col0 & 1023) >> 6;
    const float* ctp = ct + ntok * 32;
    const float* stp = st + ntok * 32;
    unsigned short xr[64];
#pragma unroll
    for (int i = 0; i < 8; ++i) {
      const int g = (hh * 8 + i) ^ (row & 7);
      *reinterpret_cast<int4*>(&xr[i * 8]) =
          *reinterpret_cast<const int4*>(&sm[row * 192 + g * 8]);
    }
    unsigned short out[64];
#pragma unroll
    for (int i = 0; i < 32; ++i) {
      const float c = ctp[i], s = stp[i];
      float o1 = b2f(xr[i]) * c - b2f(xr[2 * i + 1]) * s;        // d = i
      float o2 = b2f(xr[32 + i]) * c + b2f(xr[2 * i]) * s;       // d = 32 + i
      if (isq) { o1 *= 0.18033688f; o2 *= 0.18033688f; }         // (1/8)*log2(e)
      out[i] = f2b(o1);
      out[32 + i] = f2b(o2);
    }
    unsigned short* dst =
        (isq ? Qo : Ko) + ((size_t)((btok * 16 + h) * 2048 + ntok)) * 64;
#pragma unroll
    for (int i = 0; i < 8; ++i)
      *reinterpret_cast<int4*>(dst + i * 8) =
          *reinterpret_cast<const int4*>(&out[i * 8]);
  }
}

// ---------- out-proj GEMM: 128x128, BK=64, double-buffered (R20, measured win) ----------
__global__ __launch_bounds__(256) void gemm_out(const unsigned short* __restrict__ A,
                                                const unsigned short* __restrict__ B,
                                                float* __restrict__ C,
                                                const float* __restrict__ bias,
                                                int M, int N, int K) {
  extern __shared__ __align__(16) unsigned short sm[];  // [2][A 128x64 | B 128x64]
  const int tid = threadIdx.x, lane = tid & 63, wave = tid >> 6;
  const int lr = lane & 15, lk = lane >> 4;
  const int wr = wave >> 1, wc = wave & 1;  // 2 x 2 waves
  const int bm = blockIdx.y * 128, bn = blockIdx.x * 128;

  const int srow = tid >> 3;
  const int scol = (((tid & 7) * 16) ^ ((srow & 7) << 4)) >> 1;  // elems (swizzled)
  const unsigned short* Ag = A + (size_t)(bm + srow) * K + scol;
  const unsigned short* Bg = B + (size_t)(bn + srow) * K + scol;

  auto stage = [&](int kt, int nb) {
    const size_t ko = (size_t)kt * 64;
    unsigned short* base = sm + nb * 16384 + wave * 512;  // per-wave sub-slot
#pragma unroll
    for (int i = 0; i < 4; ++i)   // A: 128 rows (32 per issue)
      gload_lds16(Ag + (size_t)(i * 32) * K + ko, base + i * 2048);
#pragma unroll
    for (int i = 0; i < 4; ++i)   // B: 128 rows
      gload_lds16(Bg + (size_t)(i * 32) * K + ko, base + 8192 + i * 2048);
  };

  f32x4 acc[4][4] = {};
  const int swz = (lr & 7) << 4;
  const int NT = K / 64;  // 16

  stage(0, 0);
  asm volatile("s_waitcnt vmcnt(0)" ::: "memory");
  __builtin_amdgcn_s_barrier();

  for (int kt = 0; kt < NT; ++kt) {
    const int cur = kt & 1;
    const bool pf = (kt + 1 < NT);
    if (pf) stage(kt + 1, cur ^ 1);

    const unsigned short* Ab = sm + cur * 16384 + (size_t)wr * 64 * 64;
    const unsigned short* Bb = sm + cur * 16384 + 8192 + (size_t)wc * 64 * 64;

    bf16x8 b[4][2];
#pragma unroll
    for (int n = 0; n < 4; ++n)
#pragma unroll
      for (int kk = 0; kk < 2; ++kk)
        b[n][kk] = ldfrag(&Bb[(n * 16 + lr) * 64 + (((kk * 64 + lk * 16) ^ swz) >> 1)]);

#pragma unroll
    for (int m = 0; m < 4; ++m) {
      bf16x8 a[2];
#pragma unroll
      for (int kk = 0; kk < 2; ++kk)
        a[kk] = ldfrag(&Ab[(m * 16 + lr) * 64 + (((kk * 64 + lk * 16) ^ swz) >> 1)]);
      __builtin_amdgcn_s_setprio(1);
#pragma unroll
      for (int kk = 0; kk < 2; ++kk)
#pragma unroll
        for (int n = 0; n < 4; ++n)
          acc[m][n] = __builtin_amdgcn_mfma_f32_16x16x32_bf16(a[kk], b[n][kk], acc[m][n], 0, 0, 0);
      __builtin_amdgcn_s_setprio(0);
    }

    if (pf) {
      asm volatile("s_waitcnt vmcnt(0)" ::: "memory");
      __builtin_amdgcn_s_barrier();
    }
  }

  // epilogue: f32 + bias
#pragma unroll
  for (int m = 0; m < 4; ++m) {
#pragma unroll
    for (int n = 0; n < 4; ++n) {
      const int col = bn + wc * 64 + n * 16 + lr;
      const float bvv = bias[col];
#pragma unroll
      for (int r = 0; r < 4; ++r) {
        const int row = bm + wr * 64 + m * 16 + lk * 4 + r;
        C[(size_t)row * N + col] = acc[m][n][r] + bvv;
      }
    }
  }
}

// ---------- Flash attention (swapped-QK^T, in-register P, zero-shuffle PV) ----------
__global__ __launch_bounds__(512) void flash_kernel(const unsigned short* __restrict__ Q,
                                                    const unsigned short* __restrict__ Kb,
                                                    const unsigned short* __restrict__ Vt,
                                                    unsigned short* __restrict__ Out, int N) {
  extern __shared__ __align__(16) unsigned short smem[];
  unsigned short* KsB = smem;           // [2][128*64]
  unsigned short* VsB = smem + 16384;   // [2][64*128] sigma-permuted cols

  const int tid = threadIdx.x;
  const int lane = tid & 63, wave = tid >> 6;
  const int lr = lane & 15, lk = lane >> 4;
  const int bh = blockIdx.x;            // XCD pin
  const int x = blockIdx.y;             // 0..7
  const int qtA = x, qtB = 15 - x;
  const int ntA = x + 1;                // + (16-x) = 17 phases, uniform
  const unsigned short* Qh = Q + (size_t)bh * N * 64;
  const unsigned short* Kh = Kb + (size_t)bh * N * 64;
  const unsigned short* Vh = Vt + (size_t)bh * 64 * N;

  const int wrowA = qtA * 128 + wave * 16;
  const int wrowB = qtB * 128 + wave * 16;

  const int kr = tid >> 3;
  const int kcb = ((tid & 7) * 16) ^ ((kr & 7) << 4);
  const unsigned short* Kg0 = Kh + (size_t)kr * 64 + (kcb >> 1);
  const int vr = tid >> 4;
  const int vcb = ((tid & 15) * 16) ^ ((vr & 7) << 4);
  const unsigned short* Vg0 = Vh + (size_t)vr * N + (vcb >> 1);

  auto stage = [&](int buf, int tk) {
    const unsigned short* kp = Kg0 + (size_t)tk * 8192;
    const unsigned short* vp = Vg0 + (size_t)tk * 128;
    unsigned short* kl = KsB + buf * 8192 + wave * 512;
    unsigned short* vl = VsB + buf * 8192 + wave * 512;
    gload_lds16(kp, kl);
    gload_lds16(kp + 4096, kl + 4096);
    gload_lds16(vp, vl);
    gload_lds16(vp + (size_t)32 * N, vl + 4096);
  };

  stage(0, 0);

  bf16x8 qA0 = ldfrag(&Qh[(size_t)(wrowA + lr) * 64 + lk * 8]);
  bf16x8 qA1 = ldfrag(&Qh[(size_t)(wrowA + lr) * 64 + 32 + lk * 8]);
  bf16x8 qB0 = ldfrag(&Qh[(size_t)(wrowB + lr) * 64 + lk * 8]);
  bf16x8 qB1 = ldfrag(&Qh[(size_t)(wrowB + lr) * 64 + 32 + lk * 8]);

  bf16x8 ones;
  {
    union { unsigned short u; __bf16 b; } one; one.u = 0x3F80;
#pragma unroll
    for (int j = 0; j < 8; ++j) ones[j] = one.b;
  }

  const float NEG = -1e30f;  // finite sentinel: no -inf anywhere in this kernel
  f32x4 oacc[4] = {};   // O^T: [d-tile ni][d-sub r], q = lr
  f32x4 lacc = {};      // all 4 entries = l[q]
  float m_run = NEG;

  auto compute_phase = [&](int buf, bf16x8 q0, bf16x8 q1, bool diag) {
    const unsigned short* Ksb = KsB + buf * 8192;
    const unsigned short* Vsb = VsB + buf * 8192;
    f32x4 s[8];
#pragma unroll
    for (int ni = 0; ni < 8; ++ni) s[ni] = f32x4{0.f, 0.f, 0.f, 0.f};
    __builtin_amdgcn_s_setprio(1);
#pragma unroll
    for (int ni = 0; ni < 8; ++ni) {
      const int R = ni * 16 + lr;
      const int sw = (R & 7) << 4;
      bf16x8 kf0 = ldfrag(&Ksb[R * 64 + (((lk * 16) ^ sw) >> 1)]);
      bf16x8 kf1 = ldfrag(&Ksb[R * 64 + (((64 + lk * 16) ^ sw) >> 1)]);
      s[ni] = __builtin_amdgcn_mfma_f32_16x16x32_bf16(kf0, q0, s[ni], 0, 0, 0);
      s[ni] = __builtin_amdgcn_mfma_f32_16x16x32_bf16(kf1, q1, s[ni], 0, 0, 0);
    }
    __builtin_amdgcn_s_setprio(0);

    if (diag) {
      const int ql = wave * 16 + lr;
#pragma unroll
      for (int ni = 0; ni < 8; ++ni)
#pragma unroll
        for (int r = 0; r < 4; ++r)
          if (ni * 16 + lk * 4 + r > ql) s[ni][r] = NEG;
    }

    float mx = s[0][0];
#pragma unroll
    for (int ni = 0; ni < 8; ++ni)
#pragma unroll
      for (int r = 0; r < 4; ++r)
        if (ni || r) mx = fmaxf(mx, s[ni][r]);
    mx = fmaxf(mx, __shfl_xor(mx, 16, 64));
    mx = fmaxf(mx, __shfl_xor(mx, 32, 64));

    if (!__all(mx - m_run <= 8.0f)) {  // defer-max (THR=8 in log2 units)
      float nm = fmaxf(m_run, mx);
      float alpha = __builtin_amdgcn_exp2f(m_run - nm);
      m_run = nm;
#pragma unroll
      for (int ni = 0; ni < 4; ++ni) oacc[ni] *= alpha;
      lacc *= alpha;
    }

    unsigned pk[8][2];
#pragma unroll
    for (int ni = 0; ni < 8; ++ni) {
      float p0 = __builtin_amdgcn_exp2f(s[ni][0] - m_run);
      float p1 = __builtin_amdgcn_exp2f(s[ni][1] - m_run);
      float p2 = __builtin_amdgcn_exp2f(s[ni][2] - m_run);
      float p3 = __builtin_amdgcn_exp2f(s[ni][3] - m_run);
      pk[ni][0] = (unsigned)f2b_trunc(p0) | ((unsigned)f2b_trunc(p1) << 16);
      pk[ni][1] = (unsigned)f2b_trunc(p2) | ((unsigned)f2b_trunc(p3) << 16);
    }

    __builtin_amdgcn_s_setprio(1);
#pragma unroll
    for (int c = 0; c < 4; ++c) {
      union { unsigned u[4]; bf16x8 v; } pb;
      pb.u[0] = pk[2 * c][0];
      pb.u[1] = pk[2 * c][1];
      pb.u[2] = pk[2 * c + 1][0];
      pb.u[3] = pk[2 * c + 1][1];
      lacc = __builtin_amdgcn_mfma_f32_16x16x32_bf16(ones, pb.v, lacc, 0, 0, 0);
      const int cb = c * 64 + lk * 16;
#pragma unroll
      for (int ni = 0; ni < 4; ++ni) {
        const int RV = ni * 16 + lr;
        bf16x8 vf = ldfrag(&Vsb[RV * 128 + ((cb ^ ((RV & 7) << 4)) >> 1)]);
        oacc[ni] = __builtin_amdgcn_mfma_f32_16x16x32_bf16(vf, pb.v, oacc[ni], 0, 0, 0);
      }
    }
    __builtin_amdgcn_s_setprio(0);
  };

  const int b = bh >> 4, h = bh & 15;
  auto epilogue = [&](int wrow0) {
    const float rl = 1.0f / lacc[0];
    const int q = wrow0 + lr;
#pragma unroll
    for (int ni = 0; ni < 4; ++ni) {
      uint2 w;
      w.x = (unsigned)f2b(oacc[ni][0] * rl) | ((unsigned)f2b(oacc[ni][1] * rl) << 16);
      w.y = (unsigned)f2b(oacc[ni][2] * rl) | ((unsigned)f2b(oacc[ni][3] * rl) << 16);
      *reinterpret_cast<uint2*>(
          &Out[((size_t)(b * N + q)) * 1024 + h * 64 + ni * 16 + lk * 4]) = w;
    }
  };

  __syncthreads();

  int buf = 0;
  for (int p = 0; p < 17; ++p) {
    if (p + 1 < 17) {
      int tk2 = (p + 1 < ntA) ? (p + 1) : (p + 1 - ntA);
      stage(buf ^ 1, tk2);
    }
    if (p == ntA) {
      epilogue(wrowA);
#pragma unroll
      for (int ni = 0; ni < 4; ++ni) oacc[ni] = f32x4{0.f, 0.f, 0.f, 0.f};
      lacc = f32x4{0.f, 0.f, 0.f, 0.f};
      m_run = NEG;
    }
    if (p < ntA) compute_phase(buf, qA0, qA1, p == ntA - 1);
    else         compute_phase(buf, qB0, qB1, p == 16);
    __syncthreads();
    buf ^= 1;
  }
  epilogue(wrowB);
}

// ---------- launch ----------
extern "C" void kernel_launch(void* const* d_in, const int* in_sizes, int n_in,
                              void* d_out, int out_size, void* d_ws, size_t ws_size,
                              hipStream_t stream) {
  const int B = 2, N = 2048, E = 1024, C = 1024, NC = 3072;
  const int M = B * N;  // 4096

  const float* x  = (const float*)d_in[0];
  const float* Wq = (const float*)d_in[1];
  const float* bq = (const float*)d_in[2];
  const float* Wk = (const float*)d_in[3];
  const float* bk = (const float*)d_in[4];
  const float* Wv = (const float*)d_in[5];
  const float* bv = (const float*)d_in[6];
  const float* Wo = (const float*)d_in[7];
  const float* bo = (const float*)d_in[8];

  char* w = (char*)d_ws;
  size_t off = 0;
  auto alloc = [&](size_t bytes) {
    void* p = w + off;
    off += (bytes + 255) & ~(size_t)255;
    return p;
  };
  unsigned short* xb    = (unsigned short*)alloc((size_t)M * E * 2);
  unsigned short* wqkv  = (unsigned short*)alloc((size_t)NC * E * 2);
  unsigned short* wob   = (unsigned short*)alloc((size_t)E * C * 2);
  unsigned short* qb    = (unsigned short*)alloc((size_t)B * 16 * N * 64 * 2);
  unsigned short* kb    = (unsigned short*)alloc((size_t)B * 16 * N * 64 * 2);
  unsigned short* vt    = (unsigned short*)alloc((size_t)B * 16 * 64 * N * 2);
  unsigned short* attnb = (unsigned short*)alloc((size_t)M * C * 2);
  float* sin_t = (float*)alloc((size_t)N * 32 * 4);
  float* cos_t = (float*)alloc((size_t)N * 32 * 4);

  // fused prep: all bf16 casts + sin/cos table in ONE kernel (grid-stride)
  prep_kernel<<<2048, 256, 0, stream>>>(x, Wq, Wk, Wv, Wo, xb, wqkv, wob, sin_t, cos_t);

  // QKV projection + fused RoPE/relayout: 256x192 tiles, minimal-barrier K-loop
  static const int GEMM_LDS = 114688;
  hipFuncSetAttribute(reinterpret_cast<const void*>(gemm256),
                      hipFuncAttributeMaxDynamicSharedMemorySize, GEMM_LDS);
  gemm256<<<dim3((NC / 192) * (M / 256)), 512, GEMM_LDS, stream>>>(
      xb, wqkv, qb, kb, vt, sin_t, cos_t, bq, bk, bv, M, NC, E, NC / 192);

  // causal flash attention: 256 blocks x 512 thr, 64KB LDS, XCD-pinned bh
  static const int FLASH_LDS = 65536;
  hipFuncSetAttribute(reinterpret_cast<const void*>(flash_kernel),
                      hipFuncAttributeMaxDynamicSharedMemorySize, FLASH_LDS);
  flash_kernel<<<dim3(B * 16, 8), 512, FLASH_LDS, stream>>>(qb, kb, vt, attnb, N);

  // output projection: 128x128 BK=64 dbuf GEMM + bo -> f32 d_out
  static const int OUT_LDS = 65536;
  hipFuncSetAttribute(reinterpret_cast<const void*>(gemm_out),
                      hipFuncAttributeMaxDynamicSharedMemorySize, OUT_LDS);
  gemm_out<<<dim3(E / 128, M / 128), 256, OUT_LDS, stream>>>(
      attnb, wob, (float*)d_out, bo, M, E, C);
}